// Round 8
// baseline (10517.455 us; speedup 1.0000x reference)
//
#include <hip/hip_runtime.h>
#include <hip/hip_bf16.h>

typedef __attribute__((ext_vector_type(2))) _Float16 half2v;
typedef __attribute__((ext_vector_type(4))) float f32x4;

__device__ __forceinline__ unsigned short f2h_bits(float f) {
    _Float16 h = (_Float16)f;
    return __builtin_bit_cast(unsigned short, h);
}
__device__ __forceinline__ float sigf(float x) { return 1.0f / (1.0f + __expf(-x)); }
__device__ __forceinline__ float tanhf_fast(float x) {
    float ax = fabsf(x);
    float e = __expf(-2.0f * ax);             // e in (0,1], no overflow
    float t = (1.0f - e) / (1.0f + e);
    return copysignf(t, x);
}
__device__ __forceinline__ float dot2u(unsigned int w, unsigned int h, float acc) {
    return __builtin_amdgcn_fdot2(__builtin_bit_cast(half2v, w),
                                  __builtin_bit_cast(half2v, h), acc, false);
}
__device__ __forceinline__ float dot2x4(uint4 w, uint4 h, float acc) {
    acc = dot2u(w.x, h.x, acc);
    acc = dot2u(w.y, h.y, acc);
    acc = dot2u(w.z, h.z, acc);
    acc = dot2u(w.w, h.w, acc);
    return acc;
}
// Loop-carried opaque pin: forbids rematerializing weight loads (r1/r2).
__device__ __forceinline__ void pin(uint4& v) {
    asm volatile("" : "+v"(v.x), "+v"(v.y), "+v"(v.z), "+v"(v.w));
}

// K-2: zero the progress flag.
__global__ void k_flag0(int* __restrict__ prog) { *prog = 0; }

// ---------------------------------------------------------------------------
// K0: W_h fp16, packed for k_rnn v10.
// wht[gcol*256 + k] = W[256+k][gcol]; thread (gcol, K-half p) owns 16
// contiguous uint4 at offset (gcol*2+p)*16.
// ---------------------------------------------------------------------------
__global__ __launch_bounds__(256) void k_prep(const float* __restrict__ W,
                                              unsigned short* __restrict__ wht) {
    int idx = blockIdx.x * 256 + threadIdx.x;     // 262144
    int gcol = idx >> 8;
    int k    = idx & 255;
    wht[idx] = f2h_bits(W[(size_t)(256 + k) * 1024 + gcol]);
}

// K0b: carry init + fp16 h publish buffer 0 + per-batch sync counters.
// cnt[b] at prog+64+b*64 (step counter), presence[b] at +32 within the line.
__global__ __launch_bounds__(256) void k_init(const float* __restrict__ cin,
                                              const float* __restrict__ hin,
                                              float* __restrict__ cc,
                                              float* __restrict__ ch,
                                              unsigned short* __restrict__ hg,
                                              int* __restrict__ prog) {
    int i = blockIdx.x * 256 + threadIdx.x;       // 8192
    cc[i] = cin[i];
    ch[i] = hin[i];
    hg[(i >> 8) * 512 + (i & 255)] = f2h_bits(hin[i]);  // buffer 0
    if (threadIdx.x == 0) {
        int* line = (int*)((char*)prog + 64 + blockIdx.x * 64);
        line[0] = 0;                              // step counter
        line[8] = 0;                              // presence counter (+32B)
    }
}

// ---------------------------------------------------------------------------
// K1: gates chunk = x_chunk @ W_x + b, fp32 FMA (validated).
// ---------------------------------------------------------------------------
__global__ __launch_bounds__(256) void k_gates(const float* __restrict__ x,
                                               const float* __restrict__ W,
                                               const float* __restrict__ bias,
                                               float* __restrict__ gates,
                                               int C, int t0) {
    __shared__ float xs[32][256];
    int tid = threadIdx.x;
    int tc = tid & 31, tr = tid >> 5;
    int r0 = (blockIdx.x >> 3) * 32;
    int c0 = (blockIdx.x & 7) * 128;
    int b  = r0 / C;
    int tl = r0 - b * C;
    const float* xbase = x + ((size_t)b * 2048 + t0 + tl) * 256;

    for (int i = tid; i < 2048; i += 256) {
        int r = i >> 6, kq = (i & 63) << 2;
        *(f32x4*)&xs[r][kq] = *(const f32x4*)(xbase + (size_t)r * 256 + kq);
    }
    __syncthreads();

    f32x4 acc[4];
    f32x4 bb = *(const f32x4*)(bias + c0 + tc * 4);
#pragma unroll
    for (int i = 0; i < 4; ++i) acc[i] = bb;
    const float* wp = W + c0 + tc * 4;
    for (int k = 0; k < 256; k += 2) {
        f32x4 w0 = *(const f32x4*)(wp + (size_t)k * 1024);
        f32x4 w1 = *(const f32x4*)(wp + (size_t)(k + 1) * 1024);
#pragma unroll
        for (int i = 0; i < 4; ++i) {
            float2 xv = *(const float2*)&xs[tr * 4 + i][k];
            acc[i] += w0 * xv.x;
            acc[i] += w1 * xv.y;
        }
    }
#pragma unroll
    for (int i = 0; i < 4; ++i)
        *(f32x4*)(gates + (size_t)(r0 + tr * 4 + i) * 1024 + c0 + tc * 4) = acc[i];
}

// ---------------------------------------------------------------------------
// K2 v11: 4 CUs per batch, HANG-PROOF rendezvous. r7's container death taught:
// spin designs must be structurally unable to hang. Changes vs v10:
//   (1) one-shot block-wide bail latch (LDS): any wait > 2^20 spins (~50ms vs
//       legit ~us) -> prog=7, ALL threads break the t-loop, kernel exits,
//       k_diag poisons logits (decodable failure, container stays alive).
//   (2) pre-loop PRESENCE rendezvous on a separate counter verifies the 4
//       blocks of a batch are co-resident BEFORE stepping (non-cooperative
//       launch guarantees nothing; 128 blocks on 256 CUs should always fit).
// Design: block (b,g) owns 64 units. Thread = (col = gate*64+uu, p = K-half):
// 16 uint4 weights = 64 VGPRs, fully arch-register-resident. h exchanged per
// step via per-batch global fp16 dbuf; publisher = single wave (stores+
// threadfence+release-add are wave-ordered); consumer acquire invalidates its
// CU's L1 before re-staging h to LDS.
// ---------------------------------------------------------------------------
__global__ __launch_bounds__(512)
void k_rnn(const unsigned short* __restrict__ wht,
           const float* __restrict__ gates,
           const int* __restrict__ seq_lens,
           float* __restrict__ carry_c,
           float* __restrict__ carry_h,
           unsigned short* __restrict__ hg,
           int* __restrict__ prog,
           int C, int t0,
           float* __restrict__ out_ll,
           float* __restrict__ out_c,
           float* __restrict__ out_h) {
    __shared__ unsigned short hs[512];       // 2 x 256 fp16 h stage
    __shared__ float part[512];              // [p][col] partials
    __shared__ int bail;
    const int tid = threadIdx.x;             // 0..511
    const int w = tid >> 6;
    const int slot = blockIdx.x;
    const int xcd = slot & 7, idx = slot >> 3;
    const int b = xcd * 4 + (idx & 3);       // batch
    const int g = idx >> 2;                  // quarter 0..3
    const int U0 = g * 64;
    const int col = tid & 255;               // gate*64 + uu
    const int p   = tid >> 8;                // K-half
    const int gate = col >> 6, uu = col & 63;
    const int gcol = gate * 256 + U0 + uu;   // column in [0,1024)
    if (tid == 0) bail = 0;
    if (slot == 0 && tid == 0) *prog = 1;

    // 16 uint4 of weights: K-half p of column gcol — all in arch VGPRs
    const uint4* wbase = (const uint4*)wht + ((size_t)gcol * 2 + p) * 16;
    uint4 wr[16];
#pragma unroll
    for (int j = 0; j < 16; ++j) wr[j] = wbase[j];

    int ns = seq_lens[b] - t0;
    ns = ns < 0 ? 0 : (ns > C ? C : ns);
    const float* gxb = gates + (size_t)b * C * 1024;
    unsigned short* hgb = hg + (size_t)b * 512;          // 2 x 256 fp16
    int* cnt  = (int*)((char*)prog + 64 + b * 64);       // step counter
    int* pres = cnt + 8;                                 // presence (+32B)

    // ---- presence rendezvous: prove co-residency before stepping ----
    if (tid == 0) {
        __hip_atomic_fetch_add(pres, 1, __ATOMIC_RELEASE, __HIP_MEMORY_SCOPE_AGENT);
        const int ptarget = 4 * (t0 / C + 1);
        int spins = 0;
        while (__hip_atomic_load(pres, __ATOMIC_ACQUIRE,
                                 __HIP_MEMORY_SCOPE_AGENT) < ptarget) {
            __builtin_amdgcn_s_sleep(1);
            if (++spins > (1 << 20)) { bail = 1; *prog = 7; break; }
        }
    }
    __syncthreads();
    if (bail) { if (slot == 0 && tid == 0) *prog = 7; return; }
    if (slot == 0 && tid == 0) *prog = 2;

    float c = 0.f, hl = 0.f;
    if (tid < 64) {
        c  = carry_c[b * 256 + U0 + tid];
        hl = carry_h[b * 256 + U0 + tid];
    }
    // stage h(t0) into LDS (k_init wrote buffer 0; prev chunk wrote otherwise;
    // kernel-boundary ordering makes it visible)
    if (tid < 32)
        *((uint4*)hs + (t0 & 1) * 32 + tid) = *((const uint4*)hgb + (t0 & 1) * 32 + tid);
    float pg = 0.f;
    if (p == 0 && ns > 0) pg = gxb[gcol];
    __syncthreads();

    for (int t = 0; t < ns; ++t) {
        const int pr = (t0 + t) & 1;
#pragma unroll
        for (int j = 0; j < 16; ++j) pin(wr[j]);         // loop-carried residency

        float ng = 0.f;
        if (p == 0 && t + 1 < ns)                        // prefetch next seed
            ng = gxb[(size_t)(t + 1) * 1024 + gcol];

        // 64 dot2 over the thread's K-half; 4 independent chains
        const uint4* hq = (const uint4*)hs + pr * 32 + p * 16;
        float a0 = (p == 0) ? pg : 0.f, a1 = 0.f, a2 = 0.f, a3 = 0.f;
#pragma unroll
        for (int j = 0; j < 16; j += 4) {
            uint4 h0 = hq[j], h1 = hq[j + 1], h2 = hq[j + 2], h3 = hq[j + 3];
            a0 = dot2x4(wr[j],     h0, a0);
            a1 = dot2x4(wr[j + 1], h1, a1);
            a2 = dot2x4(wr[j + 2], h2, a2);
            a3 = dot2x4(wr[j + 3], h3, a3);
        }
        part[p * 256 + col] = (a0 + a1) + (a2 + a3);
        __syncthreads();                                 // (a) partials visible

        if (tid < 64) {                                  // finishers: wave 0
            float ai = part[tid]       + part[256 + tid];
            float aj = part[64 + tid]  + part[320 + tid];
            float af = part[128 + tid] + part[384 + tid];
            float ao = part[192 + tid] + part[448 + tid];
            float I = sigf(ai);
            float J = tanhf_fast(aj);
            float F = sigf(af + 1.0f);                   // FORGET_BIAS = 1.0
            float O = sigf(ao);
            c = c * F + I * J;
            float hn = tanhf_fast(c) * O;
            hl = hn;
            out_ll[(size_t)(b * 2048 + t0 + t) * 256 + U0 + tid] = hn;
            hgb[(pr ^ 1) * 256 + U0 + tid] = f2h_bits(hn);   // publish segment
        }
        if (w == 0) {
            __threadfence();                             // drain stores, L2 wb
            if (tid == 0)
                __hip_atomic_fetch_add(cnt, 1, __ATOMIC_RELEASE,
                                       __HIP_MEMORY_SCOPE_AGENT);
        }
        if (t + 1 < ns) {
            if (tid == 0) {                              // rendezvous: 4 blocks
                const int target = 4 * (t0 + t + 1);
                int spins = 0;
                while (__hip_atomic_load(cnt, __ATOMIC_ACQUIRE,
                                         __HIP_MEMORY_SCOPE_AGENT) < target) {
                    __builtin_amdgcn_s_sleep(1);
                    if (++spins > (1 << 20)) { bail = 1; *prog = 7; break; }
                }
            }
            __syncthreads();                             // (b) flag/bail visible
            if (bail) break;                             // uniform exit, no hang
            if (tid < 32) {
                __threadfence();                         // L1 inv before re-stage
                *((uint4*)hs + (pr ^ 1) * 32 + tid) =
                    *((const uint4*)hgb + (pr ^ 1) * 32 + tid);
            }
        }
        pg = ng;
        __syncthreads();                                 // (c) hs ready, part free
    }

    if (tid < 64) {
        carry_c[b * 256 + U0 + tid] = c;
        carry_h[b * 256 + U0 + tid] = hl;
        out_c[b * 256 + U0 + tid] = c;
        out_h[b * 256 + U0 + tid] = hl;
    }
    // zero rows [t0+ns, t0+C), this block's 64-unit slice
    f32x4 z = {0.f, 0.f, 0.f, 0.f};
    int cnt4 = (C - ns) * 16;                            // 16 f32x4 per row-slice
    for (int i = tid; i < cnt4; i += 512) {
        int r = i >> 4, q4 = i & 15;
        *(f32x4*)(out_ll + (size_t)(b * 2048 + t0 + ns + r) * 256 + U0 + q4 * 4) = z;
    }
    if (slot == 0 && tid == 0 && !bail) *prog = 3;
}

// ---------------------------------------------------------------------------
// K3: logits = last_layer @ W_out + b_out, fp32.
// ---------------------------------------------------------------------------
__global__ __launch_bounds__(256) void k_logits(const float* __restrict__ ll,
                                                const float* __restrict__ wout,
                                                const float* __restrict__ bout,
                                                float* __restrict__ lg) {
    __shared__ float rows[32][260];
    __shared__ float wo[4608];
    int tid = threadIdx.x;
    size_t r0 = (size_t)blockIdx.x * 32;
    for (int i = tid; i < 4608; i += 256) wo[i] = wout[i];
    const f32x4* src = (const f32x4*)(ll + r0 * 256);
    for (int i = tid; i < 2048; i += 256) {
        int row = i >> 6, c4 = (i & 63) * 4;
        *(f32x4*)&rows[row][c4] = src[i];
    }
    __syncthreads();
    for (int o = tid; o < 576; o += 256) {
        int r = o / 18, a = o - r * 18;
        float acc = bout[a];
#pragma unroll 8
        for (int k = 0; k < 256; ++k)
            acc += rows[r][k] * wo[k * 18 + a];
        lg[(r0 + r) * 18 + a] = acc;
    }
}

// ---------------------------------------------------------------------------
// K4: diagnostic collector (fires only on failure; prog==7 = sync bail).
// ---------------------------------------------------------------------------
__global__ __launch_bounds__(256) void k_diag(const float* __restrict__ gates,
                                              const int* __restrict__ prog,
                                              int wsb, int nsample,
                                              float* __restrict__ logit0) {
    __shared__ float red[256];
    int tid = threadIdx.x;
    float m = 0.f; int bad_nan = 0;
    for (int i = tid; i < nsample; i += 256) {
        float v = gates[i];
        if (v != v) bad_nan = 1;
        m = fmaxf(m, fabsf(v));
    }
    red[tid] = bad_nan ? 3.0e38f : m;
    __syncthreads();
    for (int s = 128; s > 0; s >>= 1) {
        if (tid < s) red[tid] = fmaxf(red[tid], red[tid + s]);
        __syncthreads();
    }
    if (tid == 0) {
        float l = log2f(1.0f + red[0]);
        int R = *prog; R = R < 0 ? 0 : (R > 7 ? 7 : R);
        int G = (int)(l * 0.5f); G = G < 0 ? 0 : (G > 7 ? 7 : G);
        int good = (R == 3) && (l <= 4.0f) && (wsb >= 1);
        if (!good) {
            int code = (R << 5) | (G << 2) | wsb;
            *logit0 = (float)(256 + 2 * code);
        }
    }
}

// ---------------------------------------------------------------------------
extern "C" void kernel_launch(void* const* d_in, const int* in_sizes, int n_in,
                              void* d_out, int out_size, void* d_ws, size_t ws_size,
                              hipStream_t stream) {
    // Inputs resolved by unique element count (ordering-proof).
    const float* x = nullptr; const int* seq = nullptr;
    const float* cin = nullptr, *hin = nullptr, *W = nullptr, *bia = nullptr,
               * Wo = nullptr, *bo = nullptr;
    int n8192 = 0;
    for (int i = 0; i < n_in; ++i) {
        switch (in_sizes[i]) {
            case 16777216: x   = (const float*)d_in[i]; break;
            case 32:       seq = (const int*)d_in[i];   break;
            case 524288:   W   = (const float*)d_in[i]; break;
            case 1024:     bia = (const float*)d_in[i]; break;
            case 4608:     Wo  = (const float*)d_in[i]; break;
            case 18:       bo  = (const float*)d_in[i]; break;
            case 8192:
                if (n8192 == 0) cin = (const float*)d_in[i];
                else if (n8192 == 1) hin = (const float*)d_in[i];
                ++n8192; break;
        }
    }
    if (!x)   x   = (const float*)d_in[0];
    if (!seq) seq = (const int*)d_in[1];
    if (!cin) cin = (const float*)d_in[2];
    if (!hin) hin = (const float*)d_in[3];
    if (!W)   W   = (const float*)d_in[4];
    if (!bia) bia = (const float*)d_in[5];
    if (!Wo)  Wo  = (const float*)d_in[6];
    if (!bo)  bo  = (const float*)d_in[7];

    // ws: wht fp16 512KB | carry_c 32KB | carry_h 32KB | prog+cnt 4KB |
    //     hg 32KB (32 batches x 2 x 256 fp16) | gates C*128KB
    unsigned short* wht = (unsigned short*)d_ws;
    float* carry_c = (float*)((char*)d_ws + 524288);
    float* carry_h = (float*)((char*)d_ws + 557056);
    int*   prog    = (int*)((char*)d_ws + 589824);
    unsigned short* hg = (unsigned short*)((char*)d_ws + 593920);
    float* gates   = (float*)((char*)d_ws + 626688);
    const size_t fixed = 626688;

    int wsb;
    if (ws_size < fixed + (size_t)64 * 131072) wsb = 0;
    else if (ws_size < ((size_t)70 << 20))  wsb = 1;
    else if (ws_size < ((size_t)280 << 20)) wsb = 2;
    else wsb = 3;

    int C = 2048;
    while (C > 64 && fixed + (size_t)C * 131072 > ws_size) C >>= 1;
    int NC = 2048 / C;

    // Outputs are fp32 (verified r6).
    float* out = (float*)d_out;
    float* o_logits = out;                    // 65536*18
    float* o_ll = out + 1179648;              // 65536*256
    float* o_c  = out + 17956864;             // 32*256
    float* o_h  = out + 17965056;             // 32*256

    hipLaunchKernelGGL(k_flag0, dim3(1), dim3(1), 0, stream, prog);
    int nsample = 0;
    if (wsb >= 1) {
        hipLaunchKernelGGL(k_prep, dim3(1024), dim3(256), 0, stream, W, wht);
        hipLaunchKernelGGL(k_init, dim3(32),   dim3(256), 0, stream, cin, hin,
                           carry_c, carry_h, hg, prog);
        for (int ch = 0; ch < NC; ++ch) {
            int t0 = ch * C;
            hipLaunchKernelGGL(k_gates, dim3(8 * C), dim3(256), 0, stream,
                               x, W, bia, gates, C, t0);
            hipLaunchKernelGGL(k_rnn, dim3(128), dim3(512), 0, stream,
                               wht, gates, seq, carry_c, carry_h, hg, prog, C, t0,
                               o_ll, o_c, o_h);
        }
        nsample = 4096;
    }
    hipLaunchKernelGGL(k_logits, dim3(2048), dim3(256), 0, stream, o_ll, Wo, bo, o_logits);
    hipLaunchKernelGGL(k_diag, dim3(1), dim3(256), 0, stream,
                       gates, prog, wsb, nsample, o_logits);
}

// Round 9
// 5606.782 us; speedup vs baseline: 1.8758x; 1.8758x over previous
//
#include <hip/hip_runtime.h>
#include <hip/hip_bf16.h>

typedef __attribute__((ext_vector_type(2))) _Float16 half2v;
typedef __attribute__((ext_vector_type(4))) float f32x4;

__device__ __forceinline__ unsigned short f2h_bits(float f) {
    _Float16 h = (_Float16)f;
    return __builtin_bit_cast(unsigned short, h);
}
__device__ __forceinline__ float sigf(float x) { return 1.0f / (1.0f + __expf(-x)); }
__device__ __forceinline__ float tanhf_fast(float x) {
    float ax = fabsf(x);
    float e = __expf(-2.0f * ax);             // e in (0,1], no overflow
    float t = (1.0f - e) / (1.0f + e);
    return copysignf(t, x);
}
__device__ __forceinline__ float dot2u(unsigned int w, unsigned int h, float acc) {
    return __builtin_amdgcn_fdot2(__builtin_bit_cast(half2v, w),
                                  __builtin_bit_cast(half2v, h), acc, false);
}
__device__ __forceinline__ float dot2x4(uint4 w, uint4 h, float acc) {
    acc = dot2u(w.x, h.x, acc);
    acc = dot2u(w.y, h.y, acc);
    acc = dot2u(w.z, h.z, acc);
    acc = dot2u(w.w, h.w, acc);
    return acc;
}
// Loop-carried opaque pin (proven r2: in-loop pin => true residency).
__device__ __forceinline__ void pin(uint4& v) {
    asm volatile("" : "+v"(v.x), "+v"(v.y), "+v"(v.z), "+v"(v.w));
}
// Quad all-reduce on the VALU pipe (DPP quad_perm), v6-proven correct.
// Replaces __shfl_xor (ds_swizzle = LDS pipe) — r8 accounting: the 16
// swizzles/thread were ~128 LDS wave-instrs/step on the saturated pipe.
__device__ __forceinline__ float quad_allsum(float a) {
    int y = __builtin_amdgcn_update_dpp(0, __builtin_bit_cast(int, a),
                                        0xB1 /*[1,0,3,2]*/, 0xF, 0xF, true);
    a += __builtin_bit_cast(float, y);
    y = __builtin_amdgcn_update_dpp(0, __builtin_bit_cast(int, a),
                                    0x4E /*[2,3,0,1]*/, 0xF, 0xF, true);
    a += __builtin_bit_cast(float, y);
    return a;
}

// K-2: zero the progress flag.
__global__ void k_flag0(int* __restrict__ prog) { *prog = 0; }

// ---------------------------------------------------------------------------
// K0: W_h^T fp16 [1024 gate-cols][256 k]. W fp32 [512,1024], rows 256..511.
// ---------------------------------------------------------------------------
__global__ __launch_bounds__(256) void k_prep(const float* __restrict__ W,
                                              unsigned short* __restrict__ wht) {
    int idx = blockIdx.x * 256 + threadIdx.x;     // 262144 = 1024*256
    int g = idx >> 8, k = idx & 255;
    wht[idx] = f2h_bits(W[(size_t)(256 + k) * 1024 + g]);
}

// K0b: fp32 c/h carry init.
__global__ __launch_bounds__(256) void k_init(const float* __restrict__ cin,
                                              const float* __restrict__ hin,
                                              float* __restrict__ cc,
                                              float* __restrict__ ch) {
    int i = blockIdx.x * 256 + threadIdx.x;       // 8192
    cc[i] = cin[i];
    ch[i] = hin[i];
}

// ---------------------------------------------------------------------------
// K1: gates chunk = x_chunk @ W_x + b, fp32 FMA (validated).
// ---------------------------------------------------------------------------
__global__ __launch_bounds__(256) void k_gates(const float* __restrict__ x,
                                               const float* __restrict__ W,
                                               const float* __restrict__ bias,
                                               float* __restrict__ gates,
                                               int C, int t0) {
    __shared__ float xs[32][256];
    int tid = threadIdx.x;
    int tc = tid & 31, tr = tid >> 5;
    int r0 = (blockIdx.x >> 3) * 32;
    int c0 = (blockIdx.x & 7) * 128;
    int b  = r0 / C;
    int tl = r0 - b * C;
    const float* xbase = x + ((size_t)b * 2048 + t0 + tl) * 256;

    for (int i = tid; i < 2048; i += 256) {
        int r = i >> 6, kq = (i & 63) << 2;
        *(f32x4*)&xs[r][kq] = *(const f32x4*)(xbase + (size_t)r * 256 + kq);
    }
    __syncthreads();

    f32x4 acc[4];
    f32x4 bb = *(const f32x4*)(bias + c0 + tc * 4);
#pragma unroll
    for (int i = 0; i < 4; ++i) acc[i] = bb;
    const float* wp = W + c0 + tc * 4;
    for (int k = 0; k < 256; k += 2) {
        f32x4 w0 = *(const f32x4*)(wp + (size_t)k * 1024);
        f32x4 w1 = *(const f32x4*)(wp + (size_t)(k + 1) * 1024);
#pragma unroll
        for (int i = 0; i < 4; ++i) {
            float2 xv = *(const float2*)&xs[tr * 4 + i][k];
            acc[i] += w0 * xv.x;
            acc[i] += w1 * xv.y;
        }
    }
#pragma unroll
    for (int i = 0; i < 4; ++i)
        *(f32x4*)(gates + (size_t)(r0 + tr * 4 + i) * 1024 + c0 + tc * 4) = acc[i];
}

// ---------------------------------------------------------------------------
// K2 v13: single-CU recurrence (multi-CU closed by r8: rendezvous ~3us/step
// vs 1.9us whole step). v5 base (3875us), LDS-pipe debottlenecked:
//   r8 accounting: v5 step = VALU ~73% AND LDS ~87% both near-saturated
//   (328 LDS wave-instrs/step: 8 hq + 16 iv + 16 shfl-swizzle + write).
//   v13 cuts LDS to ~136: (1) butterfly -> DPP quad_allsum (VALU pipe),
//   (2) i-gate upper K-half pinned too (56 uint4 total = 224 regs; LDS
//   weights halve to 64KB, iv reads 16->8), (3) seeds added POST-butterfly
//   on finisher lanes (kills 8 cndmask; accums start at 0).
// 512 thr, 2 waves/EU. Thread = (q = K-quarter, units 2g, 2g+1).
// ---------------------------------------------------------------------------
__global__ __launch_bounds__(512)
__attribute__((amdgpu_waves_per_eu(2, 2)))
void k_rnn(const unsigned short* __restrict__ wht,
           const float* __restrict__ gates,
           const int* __restrict__ seq_lens,
           float* __restrict__ carry_c,
           float* __restrict__ carry_h,
           int* __restrict__ prog,
           int C, int t0,
           float* __restrict__ out_ll,
           float* __restrict__ out_c,
           float* __restrict__ out_h) {
    extern __shared__ unsigned int smem[];
    uint4* ildsq = (uint4*)smem;                       // 4096 uint4 = 64KB
    unsigned short* hs = (unsigned short*)(ildsq + 4096);  // 2 x 288 ushort
    const int tid = threadIdx.x;             // 0..511
    const int w = tid >> 6, l = tid & 63;
    const int q = tid & 3;                   // K-quarter
    const int g = tid >> 2;                  // unit-pair group 0..127
    const int u0 = g * 2;
    const int b = blockIdx.x;
    if (b == 0 && tid == 0) *prog = 1;

    const uint4* whtq = (const uint4*)wht;   // col gc = whtq[gc*32 + 0..31]
    // pinned: j/f/o full K-quarter (8 uint4 each per unit) + i upper half (4)
    uint4 wj[2][8], wf[2][8], wo[2][8], wi[2][4];
#pragma unroll
    for (int uu = 0; uu < 2; ++uu) {
#pragma unroll
        for (int jj = 0; jj < 8; ++jj) {
            wj[uu][jj] = whtq[(size_t)(256 + u0 + uu) * 32 + q * 8 + jj];
            wf[uu][jj] = whtq[(size_t)(512 + u0 + uu) * 32 + q * 8 + jj];
            wo[uu][jj] = whtq[(size_t)(768 + u0 + uu) * 32 + q * 8 + jj];
        }
#pragma unroll
        for (int jj = 0; jj < 4; ++jj)
            wi[uu][jj] = whtq[(size_t)(u0 + uu) * 32 + q * 8 + 4 + jj];
    }

    // i-gate lower K-half -> LDS, lane-dense (64 consecutive uint4/wave-read)
#pragma unroll
    for (int uu = 0; uu < 2; ++uu)
#pragma unroll
        for (int jj = 0; jj < 4; ++jj)
            ildsq[(w * 8 + uu * 4 + jj) * 64 + l] =
                whtq[(size_t)(u0 + uu) * 32 + q * 8 + jj];
    if (b == 0 && tid == 0) *prog = 2;

    float c = 0.f, h = 0.f;
    if (q < 2) {
        int ua = u0 + q;
        c = carry_c[b * 256 + ua];
        h = carry_h[b * 256 + ua];
        // padded store: elem k -> ushort ((k>>3)+(k>>6))*8 + (k&7), buffer 0
        hs[((ua >> 3) + (ua >> 6)) * 8 + (ua & 7)] = f2h_bits(h);
    }
    int ns = seq_lens[b] - t0;
    ns = ns < 0 ? 0 : (ns > C ? C : ns);
    const float* gxb = gates + (size_t)b * C * 1024;
    float pg0 = 0.f, pg1 = 0.f, pg2 = 0.f, pg3 = 0.f;
    if (q < 2) {
        int ua = u0 + q;
        pg0 = gxb[ua]; pg1 = gxb[256 + ua]; pg2 = gxb[512 + ua]; pg3 = gxb[768 + ua];
    }
    const uint4* ivp = ildsq + (w * 8) * 64 + l;   // +((uu*4+j)<<6)
    __syncthreads();

    for (int t = 0; t < ns; ++t) {
        // loop-carried opacity: all 56 pinned uint4 stay register-resident
#pragma unroll
        for (int uu = 0; uu < 2; ++uu) {
#pragma unroll
            for (int jj = 0; jj < 8; ++jj) { pin(wj[uu][jj]); pin(wf[uu][jj]); pin(wo[uu][jj]); }
#pragma unroll
            for (int jj = 0; jj < 4; ++jj) pin(wi[uu][jj]);
        }

        // padded h view: uint4 i4=q*8+j sits at uint4-pos q*9+j
        const uint4* hq = (const uint4*)(hs + (t & 1) * 288) + q * 9;
        float ng0 = 0.f, ng1 = 0.f, ng2 = 0.f, ng3 = 0.f;
        if (t + 1 < ns && q < 2) {           // prefetch next seeds (1 lane/unit)
            const float* gn = gxb + (size_t)(t + 1) * 1024;
            int ua = u0 + q;
            ng0 = gn[ua]; ng1 = gn[256 + ua]; ng2 = gn[512 + ua]; ng3 = gn[768 + ua];
        }
        // pure W_h.h partial sums; x-gate seed added post-butterfly
        float a00 = 0.f, a01 = 0.f, a02 = 0.f, a03 = 0.f;
        float a10 = 0.f, a11 = 0.f, a12 = 0.f, a13 = 0.f;
#pragma unroll
        for (int j = 0; j < 4; ++j) {        // i-gate from LDS
            uint4 hv  = hq[j];
            uint4 iv0 = ivp[j << 6];
            uint4 iv1 = ivp[(4 + j) << 6];
            a00 = dot2x4(iv0,      hv, a00);
            a10 = dot2x4(iv1,      hv, a10);
            a01 = dot2x4(wj[0][j], hv, a01);
            a11 = dot2x4(wj[1][j], hv, a11);
            a02 = dot2x4(wf[0][j], hv, a02);
            a12 = dot2x4(wf[1][j], hv, a12);
            a03 = dot2x4(wo[0][j], hv, a03);
            a13 = dot2x4(wo[1][j], hv, a13);
        }
#pragma unroll
        for (int j = 4; j < 8; ++j) {        // i-gate from regs
            uint4 hv = hq[j];
            a00 = dot2x4(wi[0][j - 4], hv, a00);
            a10 = dot2x4(wi[1][j - 4], hv, a10);
            a01 = dot2x4(wj[0][j], hv, a01);
            a11 = dot2x4(wj[1][j], hv, a11);
            a02 = dot2x4(wf[0][j], hv, a02);
            a12 = dot2x4(wf[1][j], hv, a12);
            a03 = dot2x4(wo[0][j], hv, a03);
            a13 = dot2x4(wo[1][j], hv, a13);
        }
        // combine 4 K-quarters on the VALU pipe (DPP)
        a00 = quad_allsum(a00); a01 = quad_allsum(a01);
        a02 = quad_allsum(a02); a03 = quad_allsum(a03);
        a10 = quad_allsum(a10); a11 = quad_allsum(a11);
        a12 = quad_allsum(a12); a13 = quad_allsum(a13);
        if (q < 2) {
            float ai = (q ? a10 : a00) + pg0;
            float aj = (q ? a11 : a01) + pg1;
            float af = (q ? a12 : a02) + pg2;
            float ao = (q ? a13 : a03) + pg3;
            float I = sigf(ai);
            float J = tanhf_fast(aj);
            float F = sigf(af + 1.0f);       // FORGET_BIAS = 1.0
            float O = sigf(ao);
            c = c * F + I * J;
            h = tanhf_fast(c) * O;
            int ua = u0 + q;
            out_ll[(size_t)(b * 2048 + t0 + t) * 256 + ua] = h;
            hs[((t + 1) & 1) * 288 + ((ua >> 3) + (ua >> 6)) * 8 + (ua & 7)] = f2h_bits(h);
        }
        pg0 = ng0; pg1 = ng1; pg2 = ng2; pg3 = ng3;
        __syncthreads();
    }
    if (q < 2) {
        int ua = u0 + q;
        carry_c[b * 256 + ua] = c;
        carry_h[b * 256 + ua] = h;
        out_c[b * 256 + ua] = c;
        out_h[b * 256 + ua] = h;
    }
    // zero rows [t0+ns, t0+C) per dynamic_rnn semantics
    f32x4 z = {0.f, 0.f, 0.f, 0.f};
    f32x4* zp = (f32x4*)(out_ll + (size_t)(b * 2048 + t0 + ns) * 256);
    int cnt = (C - ns) * 64;                 // 64 float4 per 256-fp32 row
    for (int i = tid; i < cnt; i += 512) zp[i] = z;
    if (b == 0 && tid == 0) *prog = 3;
}

// ---------------------------------------------------------------------------
// K3: logits = last_layer @ W_out + b_out, fp32.
// ---------------------------------------------------------------------------
__global__ __launch_bounds__(256) void k_logits(const float* __restrict__ ll,
                                                const float* __restrict__ wout,
                                                const float* __restrict__ bout,
                                                float* __restrict__ lg) {
    __shared__ float rows[32][260];
    __shared__ float wo[4608];
    int tid = threadIdx.x;
    size_t r0 = (size_t)blockIdx.x * 32;
    for (int i = tid; i < 4608; i += 256) wo[i] = wout[i];
    const f32x4* src = (const f32x4*)(ll + r0 * 256);
    for (int i = tid; i < 2048; i += 256) {
        int row = i >> 6, c4 = (i & 63) * 4;
        *(f32x4*)&rows[row][c4] = src[i];
    }
    __syncthreads();
    for (int o = tid; o < 576; o += 256) {
        int r = o / 18, a = o - r * 18;
        float acc = bout[a];
#pragma unroll 8
        for (int k = 0; k < 256; ++k)
            acc += rows[r][k] * wo[k * 18 + a];
        lg[(r0 + r) * 18 + a] = acc;
    }
}

// ---------------------------------------------------------------------------
// K4: diagnostic collector (fires only on failure).
// ---------------------------------------------------------------------------
__global__ __launch_bounds__(256) void k_diag(const float* __restrict__ gates,
                                              const int* __restrict__ prog,
                                              int wsb, int nsample,
                                              float* __restrict__ logit0) {
    __shared__ float red[256];
    int tid = threadIdx.x;
    float m = 0.f; int bad_nan = 0;
    for (int i = tid; i < nsample; i += 256) {
        float v = gates[i];
        if (v != v) bad_nan = 1;
        m = fmaxf(m, fabsf(v));
    }
    red[tid] = bad_nan ? 3.0e38f : m;
    __syncthreads();
    for (int s = 128; s > 0; s >>= 1) {
        if (tid < s) red[tid] = fmaxf(red[tid], red[tid + s]);
        __syncthreads();
    }
    if (tid == 0) {
        float l = log2f(1.0f + red[0]);
        int R = *prog; R = R < 0 ? 0 : (R > 3 ? 3 : R);
        int G = (int)(l * 0.5f); G = G < 0 ? 0 : (G > 7 ? 7 : G);
        int good = (R == 3) && (l <= 4.0f) && (wsb >= 1);
        if (!good) {
            int code = (R << 5) | (G << 2) | wsb;
            *logit0 = (float)(256 + 2 * code);
        }
    }
}

// ---------------------------------------------------------------------------
extern "C" void kernel_launch(void* const* d_in, const int* in_sizes, int n_in,
                              void* d_out, int out_size, void* d_ws, size_t ws_size,
                              hipStream_t stream) {
    // Inputs resolved by unique element count (ordering-proof).
    const float* x = nullptr; const int* seq = nullptr;
    const float* cin = nullptr, *hin = nullptr, *W = nullptr, *bia = nullptr,
               * Wo = nullptr, *bo = nullptr;
    int n8192 = 0;
    for (int i = 0; i < n_in; ++i) {
        switch (in_sizes[i]) {
            case 16777216: x   = (const float*)d_in[i]; break;
            case 32:       seq = (const int*)d_in[i];   break;
            case 524288:   W   = (const float*)d_in[i]; break;
            case 1024:     bia = (const float*)d_in[i]; break;
            case 4608:     Wo  = (const float*)d_in[i]; break;
            case 18:       bo  = (const float*)d_in[i]; break;
            case 8192:
                if (n8192 == 0) cin = (const float*)d_in[i];
                else if (n8192 == 1) hin = (const float*)d_in[i];
                ++n8192; break;
        }
    }
    if (!x)   x   = (const float*)d_in[0];
    if (!seq) seq = (const int*)d_in[1];
    if (!cin) cin = (const float*)d_in[2];
    if (!hin) hin = (const float*)d_in[3];
    if (!W)   W   = (const float*)d_in[4];
    if (!bia) bia = (const float*)d_in[5];
    if (!Wo)  Wo  = (const float*)d_in[6];
    if (!bo)  bo  = (const float*)d_in[7];

    // ws: wht fp16 512KB | carry_c 32KB | carry_h 32KB | prog | gates C*128KB
    unsigned short* wht = (unsigned short*)d_ws;
    float* carry_c = (float*)((char*)d_ws + 524288);
    float* carry_h = (float*)((char*)d_ws + 557056);
    int*   prog    = (int*)((char*)d_ws + 589824);
    float* gates   = (float*)((char*)d_ws + 593920);
    const size_t fixed = 593920;

    int wsb;
    if (ws_size < fixed + (size_t)64 * 131072) wsb = 0;
    else if (ws_size < ((size_t)70 << 20))  wsb = 1;
    else if (ws_size < ((size_t)280 << 20)) wsb = 2;
    else wsb = 3;

    int C = 2048;
    while (C > 64 && fixed + (size_t)C * 131072 > ws_size) C >>= 1;
    int NC = 2048 / C;

    // Outputs are fp32 (verified r6).
    float* out = (float*)d_out;
    float* o_logits = out;                    // 65536*18
    float* o_ll = out + 1179648;              // 65536*256
    float* o_c  = out + 17956864;             // 32*256
    float* o_h  = out + 17965056;             // 32*256

    // 64KB i-weights + 2x288 ushort padded h dbuf = 65536 + 1152 = 66688
    (void)hipFuncSetAttribute(reinterpret_cast<const void*>(&k_rnn),
                              hipFuncAttributeMaxDynamicSharedMemorySize, 66688);

    hipLaunchKernelGGL(k_flag0, dim3(1), dim3(1), 0, stream, prog);
    int nsample = 0;
    if (wsb >= 1) {
        hipLaunchKernelGGL(k_prep, dim3(1024), dim3(256), 0, stream, W, wht);
        hipLaunchKernelGGL(k_init, dim3(32),   dim3(256), 0, stream, cin, hin,
                           carry_c, carry_h);
        for (int ch = 0; ch < NC; ++ch) {
            int t0 = ch * C;
            hipLaunchKernelGGL(k_gates, dim3(8 * C), dim3(256), 0, stream,
                               x, W, bia, gates, C, t0);
            hipLaunchKernelGGL(k_rnn, dim3(32), dim3(512), 66688, stream,
                               wht, gates, seq, carry_c, carry_h, prog, C, t0,
                               o_ll, o_c, o_h);
        }
        nsample = 4096;
    }
    hipLaunchKernelGGL(k_logits, dim3(2048), dim3(256), 0, stream, o_ll, Wo, bo, o_logits);
    hipLaunchKernelGGL(k_diag, dim3(1), dim3(256), 0, stream,
                       gates, prog, wsb, nsample, o_logits);
}